// Round 6
// baseline (104.096 us; speedup 1.0000x reference)
//
#include <hip/hip_runtime.h>
#include <hip/hip_bf16.h>
#include <math.h>

// ProxyMLS: score = -0.5*(e2@iv^T - 2*e@(mu*iv)^T + const_j)
// pos_e = -32*(score-0.1) = 16*raw + (16*const_j + 3.2);  neg_e = 6.4 - pos_e
// R6: 3-node pipeline. k_main = 256 blocks x 512 thr, B-resident LDS,
// A double-buffered over 8 tiles, per-column running (M,P,N) in registers
// (exact online-softmax merge) -> 4 partials/col. k_red1 deleted; k_fin
// reads the 384 KB of partials directly.

#define N_EMB 4096
#define C_CLS 8192
#define D_DIM 64
#define K_DIM 128   // concat [e^2 | e] x [iv | -2*mu*iv]

typedef __attribute__((ext_vector_type(8))) __bf16 bf16x8;
typedef __attribute__((ext_vector_type(16))) float f32x16;
typedef __attribute__((ext_vector_type(4))) int i32x4;

__device__ __forceinline__ void async_ld16(void* lds, const void* g) {
  __builtin_amdgcn_global_load_lds(
      (__attribute__((address_space(1))) void*)g,
      (__attribute__((address_space(3))) void*)lds, 16, 0, 0);
}

// One wave per row: build bf16 A=[e^2|e] (N x 128), B=[iv|-2*mu*iv] (C x 128),
// const_j = sum_d(mu^2*iv + logvar).
__global__ void k_prep(const float* __restrict__ emb,
                       const float* __restrict__ mp,
                       const float* __restrict__ lvp,
                       __bf16* __restrict__ wsA,
                       __bf16* __restrict__ wsB,
                       float* __restrict__ constv) {
  int wave = (int)((blockIdx.x * blockDim.x + threadIdx.x) >> 6);
  int lane = threadIdx.x & 63;  // lane == d (D_DIM == 64)
  if (wave < N_EMB) {
    float e = emb[wave * D_DIM + lane];
    wsA[wave * K_DIM + lane]         = (__bf16)(e * e);
    wsA[wave * K_DIM + D_DIM + lane] = (__bf16)e;
  } else {
    int j = wave - N_EMB;
    float mu = mp[j * D_DIM + lane];
    float lv = lvp[j * D_DIM + lane];
    float iv = __expf(-lv);
    wsB[j * K_DIM + lane]         = (__bf16)iv;
    wsB[j * K_DIM + D_DIM + lane] = (__bf16)(-2.0f * mu * iv);
    float t = fmaf(mu * mu, iv, lv);
    #pragma unroll
    for (int s = 32; s >= 1; s >>= 1) t += __shfl_xor(t, s);
    if (lane == 0) constv[j] = t;
  }
}

// 256 blocks x 512 thr: block = (rg, cb) covers rows rg*1024..+1024,
// cols cb*128..+128. B tile resident (32 KB), A tiles double-buffered
// (2 x 32 KB), 8 tiles of 128 rows. Wave grid 2 cols x 4 rows; per-wave
// acc = 2 x f32x16 (32x32x16 MFMA). Running (M,P,N) per column in regs,
// exact online merge per tile. XOR chunk swizzle as R2 (2-way, free).
__global__ __launch_bounds__(512, 1) void k_main(
    const __bf16* __restrict__ wsA, const __bf16* __restrict__ wsB,
    const float* __restrict__ constv, const int* __restrict__ labels,
    float* __restrict__ wsM, float* __restrict__ wsP, float* __restrict__ wsN) {
  __shared__ __align__(16) char As[2][32768];  // 64 KB (double buffer)
  __shared__ __align__(16) char Bs[32768];     // 32 KB  (96 KB -> 1 block/CU)

  const int tid = threadIdx.x;
  const int cb = blockIdx.x & 63;   // col block (C/128 = 64)
  const int rg = blockIdx.x >> 6;   // row group (4 groups of 1024 rows)

  const char* Abase = (const char*)wsA + (size_t)rg * 1024 * 256;  // bytes
  const char* Bg    = (const char*)wsB + (size_t)cb * 128 * 256;

  // Stage B (once) and A tile 0. Swizzle: LDS slot (r, cs) <- global
  // chunk (r, cs ^ (r&15)).
  #pragma unroll
  for (int it = 0; it < 4; ++it) {
    int L = it * 512 + tid;
    int r = L >> 4, cs = L & 15;
    int goff = r * 256 + ((cs ^ (r & 15)) << 4);
    async_ld16(Bs + L * 16, Bg + goff);
  }
  #pragma unroll
  for (int it = 0; it < 4; ++it) {
    int L = it * 512 + tid;
    int r = L >> 4, cs = L & 15;
    int goff = r * 256 + ((cs ^ (r & 15)) << 4);
    async_ld16(As[0] + L * 16, Abase + goff);
  }

  const int wv = tid >> 6, lane = tid & 63;
  const int wc = wv & 1, wr = wv >> 1;        // 2 col-halves x 4 row-quarters
  const int l31 = lane & 31, kg = lane >> 5;  // frag: m/n=l31, k=kg*8+j
  const int l15 = lane & 15;

  float pcv[2];
  #pragma unroll
  for (int ni = 0; ni < 2; ++ni)
    pcv[ni] = fmaf(16.0f, constv[cb * 128 + wc * 64 + ni * 32 + l31], 3.2f);

  float rM[2] = {-1e30f, -1e30f}, rP[2] = {0.f, 0.f}, rN[2] = {0.f, 0.f};

  __syncthreads();  // drains vmcnt: B + A(0) ready

  for (int t = 0; t < 8; ++t) {
    if (t < 7) {  // prefetch A(t+1) into the other buffer (freed last iter)
      const char* Agn = Abase + (size_t)(t + 1) * 32768;
      #pragma unroll
      for (int it = 0; it < 4; ++it) {
        int L = it * 512 + tid;
        int r = L >> 4, cs = L & 15;
        int goff = r * 256 + ((cs ^ (r & 15)) << 4);
        async_ld16(As[(t + 1) & 1] + L * 16, Agn + goff);
      }
    }
    const char* Ac = As[t & 1];

    f32x16 acc[2];
    #pragma unroll
    for (int ni = 0; ni < 2; ++ni)
      #pragma unroll
      for (int r = 0; r < 16; ++r) acc[ni][r] = 0.f;

    #pragma unroll
    for (int kk = 0; kk < 8; ++kk) {     // K = 8 steps of 16
      const int c = kk * 2 + kg;
      const int cofs = (c ^ l15) << 4;
      bf16x8 af = *(const bf16x8*)(Ac + (wr * 32 + l31) * 256 + cofs);
      bf16x8 b0 = *(const bf16x8*)(Bs + (wc * 64 + l31) * 256 + cofs);
      bf16x8 b1 = *(const bf16x8*)(Bs + (wc * 64 + 32 + l31) * 256 + cofs);
      acc[0] = __builtin_amdgcn_mfma_f32_32x32x16_bf16(af, b0, acc[0], 0, 0, 0);
      acc[1] = __builtin_amdgcn_mfma_f32_32x32x16_bf16(af, b1, acc[1], 0, 0, 0);
    }

    // Epilogue (regs only). C/D: col=lane&31, row=(r&3)+8*(r>>2)+4*kg.
    const int rowbase = rg * 1024 + t * 128 + wr * 32 + 4 * kg;
    i32x4 labv[4];
    #pragma unroll
    for (int g = 0; g < 4; ++g)
      labv[g] = *(const i32x4*)&labels[rowbase + 8 * g];

    #pragma unroll
    for (int ni = 0; ni < 2; ++ni) {
      const int gcol = cb * 128 + wc * 64 + ni * 32 + l31;
      float lmax = -1e30f;
      #pragma unroll
      for (int r = 0; r < 16; ++r)
        lmax = fmaxf(lmax, fmaf(16.0f, acc[ni][r], pcv[ni]));
      lmax = fmaxf(lmax, __shfl_xor(lmax, 32));  // other kg half (other rows)
      float ps = 0.f, ns = 0.f;
      #pragma unroll
      for (int r = 0; r < 16; ++r) {
        float pe = fmaf(16.0f, acc[ni][r], pcv[ni]);
        bool match = (labv[r >> 2][r & 3] == gcol);
        float v = match ? pe : (6.4f - pe);  // neg_e = 2*alpha*margin - pos_e
        float ex = __expf(v - lmax);
        ps += match ? ex : 0.f;
        ns += match ? 0.f : ex;
      }
      ps += __shfl_xor(ps, 32);
      ns += __shfl_xor(ns, 32);
      // exact online merge into running per-column state
      float nM = fmaxf(rM[ni], lmax);
      float sO = __expf(rM[ni] - nM), sN = __expf(lmax - nM);
      rP[ni] = fmaf(rP[ni], sO, ps * sN);
      rN[ni] = fmaf(rN[ni], sO, ns * sN);
      rM[ni] = nM;
    }
    __syncthreads();  // A(t) free for t+2's prefetch; A(t+1) landed
  }

  // Cross-wave merge (4 row-quarters). As[0] dead (last tile used As[1]).
  float* colred = (float*)As[0];  // [4][128][3] = 6 KB
  if (kg == 0) {
    #pragma unroll
    for (int ni = 0; ni < 2; ++ni) {
      int cl = wc * 64 + ni * 32 + l31;
      float* cr = &colred[(wr * 128 + cl) * 3];
      cr[0] = rM[ni]; cr[1] = rP[ni]; cr[2] = rN[ni];
    }
  }
  __syncthreads();
  if (tid < 128) {
    float M = -1e30f;
    #pragma unroll
    for (int w = 0; w < 4; ++w) M = fmaxf(M, colred[(w * 128 + tid) * 3]);
    float P = 0.f, Nn = 0.f;
    #pragma unroll
    for (int w = 0; w < 4; ++w) {
      const float* cr = &colred[(w * 128 + tid) * 3];
      float s = __expf(cr[0] - M);
      P = fmaf(cr[1], s, P);
      Nn = fmaf(cr[2], s, Nn);
    }
    int gcol = cb * 128 + tid;
    wsM[rg * C_CLS + gcol] = M;
    wsP[rg * C_CLS + gcol] = P;
    wsN[rg * C_CLS + gcol] = Nn;
  }
}

// Final: 1 block x 1024 thr. Merge 4 partials/col in regs, global m,
// num_valid, log1p sums. 384 KB coalesced reads.
__global__ __launch_bounds__(1024) void k_fin(
    const float* __restrict__ wsM, const float* __restrict__ wsP,
    const float* __restrict__ wsN, const int* __restrict__ labels,
    float* __restrict__ out) {
  __shared__ unsigned char flag[C_CLS];  // 8 KB
  __shared__ float sA[16], sB[16];
  __shared__ int sI[16];
  const int tid = threadIdx.x;
  const int wv = tid >> 6, lane = tid & 63;

  float colM[8], colP[8], colN[8];
  float gm = -1e30f;
  #pragma unroll
  for (int k = 0; k < 8; ++k) {
    int j = k * 1024 + tid;
    float m0 = wsM[0 * C_CLS + j], m1 = wsM[1 * C_CLS + j];
    float m2 = wsM[2 * C_CLS + j], m3 = wsM[3 * C_CLS + j];
    float M = fmaxf(fmaxf(m0, m1), fmaxf(m2, m3));
    float s0 = __expf(m0 - M), s1 = __expf(m1 - M);
    float s2 = __expf(m2 - M), s3 = __expf(m3 - M);
    colM[k] = M;
    colP[k] = fmaf(wsP[0 * C_CLS + j], s0, fmaf(wsP[1 * C_CLS + j], s1,
              fmaf(wsP[2 * C_CLS + j], s2, wsP[3 * C_CLS + j] * s3)));
    colN[k] = fmaf(wsN[0 * C_CLS + j], s0, fmaf(wsN[1 * C_CLS + j], s1,
              fmaf(wsN[2 * C_CLS + j], s2, wsN[3 * C_CLS + j] * s3)));
    gm = fmaxf(gm, M);
  }

  for (int i = tid; i < C_CLS; i += 1024) flag[i] = 0;
  __syncthreads();
  for (int i = tid; i < N_EMB; i += 1024) flag[labels[i]] = 1;
  __syncthreads();
  int nv = 0;
  #pragma unroll
  for (int k = 0; k < 8; ++k) nv += flag[k * 1024 + tid];
  #pragma unroll
  for (int s = 32; s >= 1; s >>= 1) {
    gm = fmaxf(gm, __shfl_xor(gm, s));
    nv += __shfl_xor(nv, s);
  }
  if (lane == 0) { sA[wv] = gm; sI[wv] = nv; }
  __syncthreads();
  if (tid == 0) {
    float mm = -1e30f; int n = 0;
    #pragma unroll
    for (int k = 0; k < 16; ++k) { mm = fmaxf(mm, sA[k]); n += sI[k]; }
    sA[0] = mm; sI[0] = n;
  }
  __syncthreads();
  const float m = sA[0];
  const int num_valid = sI[0];
  __syncthreads();
  float pt = 0.f, nt = 0.f;
  #pragma unroll
  for (int k = 0; k < 8; ++k) {
    float s = __expf(colM[k] - m);
    pt += log1pf(colP[k] * s);
    nt += log1pf(colN[k] * s);
  }
  #pragma unroll
  for (int s = 32; s >= 1; s >>= 1) {
    pt += __shfl_xor(pt, s);
    nt += __shfl_xor(nt, s);
  }
  if (lane == 0) { sA[wv] = pt; sB[wv] = nt; }
  __syncthreads();
  if (tid == 0) {
    float sp = 0.f, sn = 0.f;
    #pragma unroll
    for (int k = 0; k < 16; ++k) { sp += sA[k]; sn += sB[k]; }
    out[0] = (sp + (float)C_CLS * m) / (float)num_valid
           + (sn + (float)C_CLS * m) / (float)C_CLS;
  }
}

extern "C" void kernel_launch(void* const* d_in, const int* in_sizes, int n_in,
                              void* d_out, int out_size, void* d_ws, size_t ws_size,
                              hipStream_t stream) {
  const float* emb    = (const float*)d_in[0];
  const int*   labels = (const int*)d_in[1];
  const float* mp     = (const float*)d_in[2];
  const float* lvp    = (const float*)d_in[3];
  float* out = (float*)d_out;

  char* ws = (char*)d_ws;
  __bf16* wsA   = (__bf16*)ws;                            // 4096*128*2 = 1 MB
  __bf16* wsB   = (__bf16*)(ws + (1u << 20));             // 8192*128*2 = 2 MB
  float* constv = (float*)(ws + 3u * (1u << 20));         // 32 KB
  float* wsM    = (float*)(ws + 3u * (1u << 20) + (1u << 15));  // 4*8192*4 = 128 KB
  float* wsP    = wsM + 4 * C_CLS;                        // 128 KB
  float* wsN    = wsP + 4 * C_CLS;                        // 128 KB

  hipLaunchKernelGGL(k_prep, dim3((N_EMB + C_CLS) / 4), dim3(256), 0, stream,
                     emb, mp, lvp, wsA, wsB, constv);
  hipLaunchKernelGGL(k_main, dim3(4 * (C_CLS / 128)), dim3(512), 0, stream,
                     wsA, wsB, constv, labels, wsM, wsP, wsN);
  hipLaunchKernelGGL(k_fin, dim3(1), dim3(1024), 0, stream,
                     wsM, wsP, wsN, labels, out);
}